// Round 3
// baseline (76.791 us; speedup 1.0000x reference)
//
#include <hip/hip_runtime.h>

#define DENSE 2048
#define BATCH 64
#define MAXS  1024

typedef __attribute__((ext_vector_type(8))) __bf16 bf16x8;
typedef __attribute__((ext_vector_type(4))) float f32x4;

// Single-kernel fused design (R3). R1 proved grid.sync costs ~67 us idle ->
// fusion must have ZERO inter-block dependencies. Trick: ids is only 256 KB
// (L2-resident), so each block rebuilds the histogram slice it needs in LDS.
//
// Block = (j-tile of 16 cols, batch-quarter of 16 rows), grid 512 = 128 x 4.
//   bid = bq*128 + jt  -> the 4 blocks sharing a j-tile's W rows are congruent
//   mod 8 -> same XCD under round-robin -> W L2 reuse x4.
// Each block:
//   1. issue ids loads (16 int4/thread, its 16 batches = 64 KB, L2-hot)
//   2. issue ALL W loads (32 f32x4/thread = its 16 rows x 2048 k, HBM long pole)
//   3. histogram into packed-u16 LDS cnt[16][2048] (64 KB) while W is in flight
//      - atomicAdd 1<<((k&1)*16) on u32 words; counts <=1024, no carry-out
//      - XOR swizzle byte ^= (b&7)<<4: the A-frag ds_read_b128 pattern
//        (16 lanes @ stride 4096 B) would be 16-way bank-conflicted; swizzle
//        makes it 2-way (free, m136)
//   4. per k-step: b128-read 8 counts, unpack u16->bf16 (exactly once per
//      (b,k) block-wide), mfma_f32_16x16x32_bf16 into acc
//   5. 4-wave LDS reduce (P aliases cnt buffer after a sync), PLAIN stores.
// No atomics to global, no zero-init, no workspace, no second dispatch.
//
// A-frag layout (verified R2, absmax 1.0): lane l, elem i holds
//   A[m = l&15][k = (l>>4)*8 + i];  B-frag: B[k = (l>>4)*8+i][n = l&15];
//   C/D: row = (l>>4)*4 + reg, col = l&15.

__global__ __launch_bounds__(256, 2) void fused_kernel(
        const int* __restrict__ ids, const int* __restrict__ ns,
        const float* __restrict__ W, float* __restrict__ out) {
    __shared__ unsigned int lds[16 * 1024];   // 64 KB: cnt16[16][2048]; P alias

    const int tid  = threadIdx.x;
    const int bid  = blockIdx.x;
    const int jt   = bid & 127;         // j tile
    const int bq   = bid >> 7;          // batch quarter 0..3
    const int lane = tid & 63;
    const int wv   = tid >> 6;          // wave 0..3 owns k-quarter
    const int ln   = lane & 15;         // j within tile / b_local for A-frag
    const int lq   = lane >> 4;         // k quad
    const int j0   = jt * 16;
    const int step0 = wv * 16;          // 16 k-steps of 32 per wave
    const float* wrow = W + (size_t)(j0 + ln) * DENSE;

    // --- zero cnt: 16384 words / 256 thr = 16 int4 per thread (no VMEM)
    #pragma unroll
    for (int z = 0; z < 16; ++z)
        ((int4*)lds)[z * 256 + tid] = int4{0, 0, 0, 0};

    // --- issue ids loads FIRST (vmcnt is FIFO: consuming these must not wait
    //     on the W loads issued after them)
    int4 idv[16];
    const int* idbase = ids + (size_t)bq * 16 * MAXS;
    #pragma unroll
    for (int c = 0; c < 16; ++c)
        idv[c] = ((const int4*)(idbase + c * MAXS))[tid];

    // --- issue ALL W loads (HBM long pole; latency hides under histogram)
    f32x4 w0[16], w1[16];
    #pragma unroll
    for (int s = 0; s < 16; ++s) {
        const int kbase = (step0 + s) * 32 + lq * 8;
        w0[s] = *(const f32x4*)(wrow + kbase);
        w1[s] = *(const f32x4*)(wrow + kbase + 4);
    }

    __syncthreads();   // cnt zeroed

    // --- histogram: thread t handles ids[b_local][t*4 .. t*4+3] for 16 b's
    const int base = tid * 4;
    #pragma unroll
    for (int c = 0; c < 16; ++c) {
        const int n = ns[bq * 16 + c];          // uniform -> s_load
        const int4 v = idv[c];
        const int ks[4] = {v.x, v.y, v.z, v.w};
        #pragma unroll
        for (int e = 0; e < 4; ++e) {
            if (base + e < n) {
                const unsigned k = (unsigned)ks[e];
                const unsigned byte0 = ((unsigned)c << 12) | ((k >> 1) << 2);
                const unsigned swz = byte0 ^ ((unsigned)(c & 7) << 4);
                atomicAdd(&lds[swz >> 2], 1u << ((k & 1) << 4));
            }
        }
    }
    __syncthreads();   // histogram complete

    // --- MFMA over this wave's 16 k-steps
    f32x4 acc = (f32x4)0.0f;
    #pragma unroll
    for (int s = 0; s < 16; ++s) {
        // A-frag: 8 contiguous u16 counts = one swizzled ds_read_b128
        const unsigned abyte = ((unsigned)ln << 12) + (unsigned)((step0 + s) * 64)
                             + ((unsigned)lq << 4);
        const uint4 cw = *(const uint4*)((const char*)lds + (abyte ^ ((unsigned)(ln & 7) << 4)));
        bf16x8 a;
        a[0] = (__bf16)(float)(cw.x & 0xFFFFu);  a[1] = (__bf16)(float)(cw.x >> 16);
        a[2] = (__bf16)(float)(cw.y & 0xFFFFu);  a[3] = (__bf16)(float)(cw.y >> 16);
        a[4] = (__bf16)(float)(cw.z & 0xFFFFu);  a[5] = (__bf16)(float)(cw.z >> 16);
        a[6] = (__bf16)(float)(cw.w & 0xFFFFu);  a[7] = (__bf16)(float)(cw.w >> 16);
        bf16x8 wb;
        #pragma unroll
        for (int i = 0; i < 4; ++i) {
            wb[i]     = (__bf16)w0[s][i];
            wb[i + 4] = (__bf16)w1[s][i];
        }
        acc = __builtin_amdgcn_mfma_f32_16x16x32_bf16(a, wb, acc, 0, 0, 0);
    }

    // --- cross-wave reduce: alias P[4][4][65] (padded) into the cnt buffer
    __syncthreads();   // all cnt reads done; safe to overwrite lds
    float* P = (float*)lds;
    #pragma unroll
    for (int r = 0; r < 4; ++r)
        P[(wv * 4 + r) * 65 + lane] = acc[r];
    __syncthreads();

    // thread t -> out[bq*16 + bpart][j0 + jloc], plain coalesced store
    const int jloc  = tid & 15;
    const int bpart = tid >> 4;                       // 0..15
    const int lsrc  = ((bpart >> 2) << 4) | jloc;     // source lane
    const int r     = bpart & 3;                      // source acc reg
    float v = 0.0f;
    #pragma unroll
    for (int w = 0; w < 4; ++w)
        v += P[(w * 4 + r) * 65 + lsrc];
    out[(size_t)(bq * 16 + bpart) * DENSE + j0 + jloc] = v;
}

extern "C" void kernel_launch(void* const* d_in, const int* in_sizes, int n_in,
                              void* d_out, int out_size, void* d_ws, size_t ws_size,
                              hipStream_t stream) {
    const int*   ids = (const int*)d_in[0];   // [64, 1024] int32
    const int*   ns  = (const int*)d_in[1];   // [64] int32
    const float* W   = (const float*)d_in[2]; // [2048, 2048] float32
    float*  out = (float*)d_out;              // [64, 2048] float32
    (void)d_ws; (void)ws_size;                // no workspace needed anymore

    hipLaunchKernelGGL(fused_kernel, dim3(512), dim3(256), 0, stream, ids, ns, W, out);
}

// Round 4
// 76.624 us; speedup vs baseline: 1.0022x; 1.0022x over previous
//
#include <hip/hip_runtime.h>

#define DENSE 2048
#define BATCH 64
#define MAXS  1024

typedef __attribute__((ext_vector_type(8))) __bf16 bf16x8;
typedef __attribute__((ext_vector_type(4))) float f32x4;

// Single fused kernel, R4 = R3 algorithm with a corrected schedule.
// R3 defects fixed here:
//   1. The cnt-zero __syncthreads now comes BEFORE any VMEM issue. hipcc
//      drains vmcnt(0) at every barrier, so R3's post-issue barrier
//      serialized the whole W fetch before the histogram. Now: barrier
//      (lgkm-only, cheap) -> issue ids -> issue W half-1 -> hist runs while
//      W flies (FIFO waitcnt: ids consumption leaves W outstanding).
//   2. Register hoard halved: only 8 of 16 W k-steps preloaded (64 VGPR
//      instead of 128) across the hist phase; the other half is issued
//      after the post-hist barrier and its latency hides under the first
//      half's cvt+MFMA. Peak live ~150 VGPR < 256 cap -> no spills.
//
// Block = (j-tile of 16, batch-quarter of 16), grid 512 = 128 x 4, 2 blk/CU.
// bid = bq*128 + jt -> the 4 blocks sharing a j-tile's W rows are congruent
// mod 8 -> same XCD -> W fetched once from HBM (16.8 MB), x4 served by L2.
// Each block rebuilds its 16-batch histogram in LDS (ids is L2-resident;
// redundancy is ~1 us of L2 traffic, hidden under the W HBM pole).
// Plain stores, no atomics to global, no workspace, no second dispatch.
//
// Verified pieces kept byte-identical (R3 passed absmax 1.0):
//   - packed-u16 cnt with XOR swizzle byte ^= (b&7)<<4 (A-frag ds_read_b128
//     pattern: 16 lanes @ 4 KB stride -> 2-way instead of 16-way conflict)
//   - A-frag unpack, B-frag cvt, MFMA 16x16x32, C/D mapping, LDS reduce.

__global__ __launch_bounds__(256, 2) void fused_kernel(
        const int* __restrict__ ids, const int* __restrict__ ns,
        const float* __restrict__ W, float* __restrict__ out) {
    __shared__ unsigned int lds[16 * 1024];   // 64 KB: cnt16[16][2048]; P alias

    const int tid  = threadIdx.x;
    const int bid  = blockIdx.x;
    const int jt   = bid & 127;         // j tile
    const int bq   = bid >> 7;          // batch quarter 0..3
    const int lane = tid & 63;
    const int wv   = tid >> 6;          // wave 0..3 owns k-quarter
    const int ln   = lane & 15;         // j within tile / b_local for A-frag
    const int lq   = lane >> 4;         // k quad
    const int j0   = jt * 16;
    const int step0 = wv * 16;          // 16 k-steps of 32 per wave
    const float* wrow = W + (size_t)(j0 + ln) * DENSE;

    // --- zero cnt, then barrier BEFORE any VMEM (waits lgkm only)
    #pragma unroll
    for (int z = 0; z < 16; ++z)
        ((int4*)lds)[z * 256 + tid] = int4{0, 0, 0, 0};
    __syncthreads();

    // --- issue ids loads first (oldest in vmcnt FIFO: consuming them never
    //     forces the W loads issued after them to drain)
    int4 idv[16];
    const int* idbase = ids + (size_t)bq * 16 * MAXS;
    #pragma unroll
    for (int c = 0; c < 16; ++c)
        idv[c] = ((const int4*)(idbase + c * MAXS))[tid];

    // --- issue W HALF 1 (k-steps 0..7): 64 VGPR, latency hides under hist
    f32x4 w0[8], w1[8];
    #pragma unroll
    for (int s = 0; s < 8; ++s) {
        const int kbase = (step0 + s) * 32 + lq * 8;
        w0[s] = *(const f32x4*)(wrow + kbase);
        w1[s] = *(const f32x4*)(wrow + kbase + 4);
    }

    // --- histogram (identical math to R3, verified absmax 1.0)
    const int base = tid * 4;
    #pragma unroll
    for (int c = 0; c < 16; ++c) {
        const int n = ns[bq * 16 + c];          // uniform -> s_load
        const int4 v = idv[c];
        const int ks[4] = {v.x, v.y, v.z, v.w};
        #pragma unroll
        for (int e = 0; e < 4; ++e) {
            if (base + e < n) {
                const unsigned k = (unsigned)ks[e];
                const unsigned byte0 = ((unsigned)c << 12) | ((k >> 1) << 2);
                const unsigned swz = byte0 ^ ((unsigned)(c & 7) << 4);
                atomicAdd(&lds[swz >> 2], 1u << ((k & 1) << 4));
            }
        }
    }
    __syncthreads();   // histogram complete (drains W half-1 remnants only)

    // --- issue W HALF 2 now; its latency hides under half-1 cvt+MFMA
    f32x4 w2[8], w3[8];
    #pragma unroll
    for (int s = 0; s < 8; ++s) {
        const int kbase = (step0 + 8 + s) * 32 + lq * 8;
        w2[s] = *(const f32x4*)(wrow + kbase);
        w3[s] = *(const f32x4*)(wrow + kbase + 4);
    }

    f32x4 acc = (f32x4)0.0f;
    #pragma unroll
    for (int s = 0; s < 16; ++s) {
        // A-frag: 8 contiguous u16 counts = one swizzled ds_read_b128
        const unsigned abyte = ((unsigned)ln << 12) + (unsigned)((step0 + s) * 64)
                             + ((unsigned)lq << 4);
        const uint4 cw = *(const uint4*)((const char*)lds + (abyte ^ ((unsigned)(ln & 7) << 4)));
        bf16x8 a;
        a[0] = (__bf16)(float)(cw.x & 0xFFFFu);  a[1] = (__bf16)(float)(cw.x >> 16);
        a[2] = (__bf16)(float)(cw.y & 0xFFFFu);  a[3] = (__bf16)(float)(cw.y >> 16);
        a[4] = (__bf16)(float)(cw.z & 0xFFFFu);  a[5] = (__bf16)(float)(cw.z >> 16);
        a[6] = (__bf16)(float)(cw.w & 0xFFFFu);  a[7] = (__bf16)(float)(cw.w >> 16);
        const f32x4 wa = (s < 8) ? w0[s & 7] : w2[s & 7];   // s constant after unroll
        const f32x4 wc = (s < 8) ? w1[s & 7] : w3[s & 7];
        bf16x8 wb;
        #pragma unroll
        for (int i = 0; i < 4; ++i) {
            wb[i]     = (__bf16)wa[i];
            wb[i + 4] = (__bf16)wc[i];
        }
        acc = __builtin_amdgcn_mfma_f32_16x16x32_bf16(a, wb, acc, 0, 0, 0);
    }

    // --- cross-wave reduce: alias P[16 rows][65] (padded) into cnt buffer
    __syncthreads();   // all cnt reads done; safe to overwrite lds
    float* P = (float*)lds;
    #pragma unroll
    for (int r = 0; r < 4; ++r)
        P[(wv * 4 + r) * 65 + lane] = acc[r];
    __syncthreads();

    // thread t -> out[bq*16 + bpart][j0 + jloc], plain coalesced store
    const int jloc  = tid & 15;
    const int bpart = tid >> 4;                       // 0..15
    const int lsrc  = ((bpart >> 2) << 4) | jloc;     // source lane
    const int r     = bpart & 3;                      // source acc reg
    float v = 0.0f;
    #pragma unroll
    for (int w = 0; w < 4; ++w)
        v += P[(w * 4 + r) * 65 + lsrc];
    out[(size_t)(bq * 16 + bpart) * DENSE + j0 + jloc] = v;
}

extern "C" void kernel_launch(void* const* d_in, const int* in_sizes, int n_in,
                              void* d_out, int out_size, void* d_ws, size_t ws_size,
                              hipStream_t stream) {
    const int*   ids = (const int*)d_in[0];   // [64, 1024] int32
    const int*   ns  = (const int*)d_in[1];   // [64] int32
    const float* W   = (const float*)d_in[2]; // [2048, 2048] float32
    float*  out = (float*)d_out;              // [64, 2048] float32
    (void)d_ws; (void)ws_size;                // no workspace needed

    hipLaunchKernelGGL(fused_kernel, dim3(512), dim3(256), 0, stream, ids, ns, W, out);
}

// Round 5
// 72.235 us; speedup vs baseline: 1.0631x; 1.0608x over previous
//
#include <hip/hip_runtime.h>

#define DENSE 2048
#define BATCH 64
#define MAXS  1024

typedef __attribute__((ext_vector_type(8))) __bf16 bf16x8;
typedef __attribute__((ext_vector_type(4))) float f32x4;

// REVERT to the R0 two-kernel structure (71.4 us, best measured) after the
// fused single-kernel family (R3/R4 ~76.7) proved structurally slower:
// fusion traded exact-once W traffic (512 x 32 KB = 16 MB, no amplification)
// for 4x L2-amplified W + 8x-redundant histograms. Only byte-level trims
// retained here:
//   - hist: Cbf written as one coalesced bf16x8 (16 B) store per thread
//     (R2-verified mapping) instead of 8 scattered 2 B stores; cnt-zero and
//     out-zero vectorized (int4 / f32x4).
//   - spmm: VERBATIM R0 (proven). W loads before A loads, plain cached
//     loads (NT regressed R3-prev-session), conflict-free epilogue LDS,
//     4-way k-split atomics into zeroed out (4 contenders share an XCD:
//     bid, bid+128, bid+256, bid+384 congruent mod 8).
//
// Cbf layout (verified, absmax 1.0): lane = (b&15) | (((k>>3)&3)<<4) holds
//   C[b = mt*16+(lane&15)][k = ks*32+(lane>>4)*8+i]  (A-frag, mfma 16x16x32 bf16)

__global__ __launch_bounds__(256) void hist_kernel(const int* __restrict__ ids,
                                                   const int* __restrict__ ns,
                                                   __bf16* __restrict__ Cbf,
                                                   float* __restrict__ out) {
    __shared__ int cnt[DENSE];
    const int b = blockIdx.x;
    const int tid = threadIdx.x;
    // zero 2048 ints = 2 int4 per thread
    ((int4*)cnt)[tid]       = int4{0, 0, 0, 0};
    ((int4*)cnt)[tid + 256] = int4{0, 0, 0, 0};
    __syncthreads();
    const int n = ns[b];
    const int4 v = ((const int4*)(ids + b * MAXS))[tid];  // 1024 = 256*int4
    const int base = tid * 4;
    if (base + 0 < n) atomicAdd(&cnt[v.x], 1);
    if (base + 1 < n) atomicAdd(&cnt[v.y], 1);
    if (base + 2 < n) atomicAdd(&cnt[v.z], 1);
    if (base + 3 < n) atomicAdd(&cnt[v.w], 1);
    __syncthreads();
    // zero this batch's out row (spmm atomics accumulate into it):
    // 2048 floats = 2 f32x4 per thread, streaming coalesced
    f32x4* orow = (f32x4*)(out + (size_t)b * DENSE);
    orow[tid]       = (f32x4)0.0f;
    orow[tid + 256] = (f32x4)0.0f;
    // Cbf: thread tid -> k = tid*8 .. tid*8+7: (k>>3)&3 = tid&3, k>>5 = tid>>2,
    // k&7 = 0..7 consecutive -> one aligned 16 B bf16x8 store (R2-verified).
    const int mt = b >> 4;
    const int bl = b & 15;
    const int l2 = bl | ((tid & 3) << 4);
    const size_t off = ((size_t)((tid >> 2) * 4 + mt) * 64 + l2) * 8;
    const int4 c0 = ((const int4*)cnt)[tid * 2];
    const int4 c1 = ((const int4*)cnt)[tid * 2 + 1];
    bf16x8 o;
    o[0] = (__bf16)(float)c0.x;  o[1] = (__bf16)(float)c0.y;
    o[2] = (__bf16)(float)c0.z;  o[3] = (__bf16)(float)c0.w;
    o[4] = (__bf16)(float)c1.x;  o[5] = (__bf16)(float)c1.y;
    o[6] = (__bf16)(float)c1.z;  o[7] = (__bf16)(float)c1.w;
    *(bf16x8*)(Cbf + off) = o;
}

// spmm: out[b][j] += sum_k C[b][k] * W[j][k] via bf16 MFMA 16x16x32.
// VERBATIM R0 (71.4 us proven): grid (128 j-tiles, 4 k-splits), 4 waves/block,
// 4 k-steps/wave. W loads issued before A loads (W = HBM long pole, A = L2/L3
// hit), conflict-free epilogue LDS layout.
__global__ __launch_bounds__(256) void spmm_kernel(const float* __restrict__ W,
                                                   const __bf16* __restrict__ Cbf,
                                                   float* __restrict__ out) {
    const int tid  = threadIdx.x;
    const int lane = tid & 63;
    const int wv   = tid >> 6;          // 0..3
    const int j0   = blockIdx.x * 16;   // j tile
    const int ks4  = blockIdx.y;        // 0..3 k split

    const int ln = lane & 15;           // j index within tile (B-frag n)
    const int lq = lane >> 4;           // k quad 0..3

    const int step0 = ks4 * 16 + wv * 4;
    const float* wrow = W + (size_t)(j0 + ln) * DENSE;

    // --- W loads first (HBM long pole; plain cached loads)
    f32x4 w0[4], w1[4];
    #pragma unroll
    for (int s = 0; s < 4; ++s) {
        const int kbase = (step0 + s) * 32 + lq * 8;
        w0[s] = *(const f32x4*)(wrow + kbase);
        w1[s] = *(const f32x4*)(wrow + kbase + 4);
    }
    // --- A-frag loads (Cbf is L2/L3-resident)
    bf16x8 afr[4][4];
    #pragma unroll
    for (int s = 0; s < 4; ++s) {
        #pragma unroll
        for (int mt = 0; mt < 4; ++mt) {
            afr[s][mt] = *(const bf16x8*)(Cbf + ((size_t)((step0 + s) * 4 + mt) * 64 + lane) * 8);
        }
    }

    bf16x8 wb[4];
    #pragma unroll
    for (int s = 0; s < 4; ++s) {
        #pragma unroll
        for (int i = 0; i < 4; ++i) {
            wb[s][i]     = (__bf16)w0[s][i];
            wb[s][i + 4] = (__bf16)w1[s][i];
        }
    }

    f32x4 acc[4];
    #pragma unroll
    for (int mt = 0; mt < 4; ++mt) acc[mt] = (f32x4)0.0f;
    #pragma unroll
    for (int s = 0; s < 4; ++s) {
        #pragma unroll
        for (int mt = 0; mt < 4; ++mt) {
            acc[mt] = __builtin_amdgcn_mfma_f32_16x16x32_bf16(afr[s][mt], wb[s], acc[mt], 0, 0, 0);
        }
    }

    // --- cross-wave reduction, conflict-free layout P[wv][mt][r][lane]
    __shared__ float P[4][4][4][64];    // 16 KB
    #pragma unroll
    for (int mt = 0; mt < 4; ++mt) {
        #pragma unroll
        for (int r = 0; r < 4; ++r) {
            P[wv][mt][r][lane] = acc[mt][r];
        }
    }
    __syncthreads();

    // thread t -> (jloc = t&15 fastest for coalesced atomics, bpart = t>>4)
    const int jloc  = tid & 15;
    const int bpart = tid >> 4;                       // 0..15
    const int lsrc  = ((bpart >> 2) << 4) | jloc;     // source lane
    const int r     = bpart & 3;                      // source acc reg
    #pragma unroll
    for (int mt = 0; mt < 4; ++mt) {
        const float v = P[0][mt][r][lsrc] + P[1][mt][r][lsrc]
                      + P[2][mt][r][lsrc] + P[3][mt][r][lsrc];
        atomicAdd(&out[(size_t)(mt * 16 + bpart) * DENSE + j0 + jloc], v);
    }
}

extern "C" void kernel_launch(void* const* d_in, const int* in_sizes, int n_in,
                              void* d_out, int out_size, void* d_ws, size_t ws_size,
                              hipStream_t stream) {
    const int*   ids = (const int*)d_in[0];   // [64, 1024] int32
    const int*   ns  = (const int*)d_in[1];   // [64] int32
    const float* W   = (const float*)d_in[2]; // [2048, 2048] float32
    float*  out = (float*)d_out;              // [64, 2048] float32
    __bf16* Cbf = (__bf16*)d_ws;              // 64*2048 bf16 = 256 KB

    hipLaunchKernelGGL(hist_kernel, dim3(BATCH), dim3(256), 0, stream, ids, ns, Cbf, out);
    hipLaunchKernelGGL(spmm_kernel, dim3(128, 4), dim3(256), 0, stream, W, Cbf, out);
}